// Round 1
// baseline (852.553 us; speedup 1.0000x reference)
//
#include <hip/hip_runtime.h>

// CSAA: resize 1x1 conv -> width axial attn -> height axial attn -> restore 1x1 conv.
// B=8, CIN=256, COUT=256, R=H=W=128.
// Everything is expressed as a batched tiled GEMM with template flags:
//   AT: A operand is m-fast (a_mstride==1) instead of k-fast (a_kstride==1)
//   BT: B operand is k-fast (b_kstride==1) instead of n-fast (b_nstride==1)
//   SM: fuse row softmax (over the n dimension, requires M=N=128, single tile)
// Per-block tile: 128(m) x 128(n), 256 threads, 8x8 outputs/thread, K-chunks of 32.

#define KC   32
#define LPAD 132   // LDS row stride (floats); 132*4=528B, 16B-aligned, breaks pow2 banks

template<bool AT, bool BT, bool SM>
__global__ __launch_bounds__(256)
void gemm_k(const float* __restrict__ Aptr, const float* __restrict__ Bptr,
            const float* __restrict__ bias, float* __restrict__ Cptr,
            int K,
            long long a_bstride, int a_mstride, int a_kstride,
            long long b_bhi, int b_shift, int b_bmask, int b_blo,
            int b_kstride, int b_nstride,
            long long c_bhi, int c_shift, int c_bmask, int c_blo,
            int c_mstride)
{
    __shared__ float As[KC][LPAD];
    __shared__ float Bs[KC][LPAD];

    const int tid = threadIdx.x;
    const int tr  = tid >> 4;    // 0..15  (m sub-block)
    const int tc  = tid & 15;    // 0..15  (n sub-block)
    const int n0  = blockIdx.x * 128;
    const int m0  = blockIdx.y * 128;
    const int bb  = blockIdx.z;

    const float* Ab = Aptr + (long long)bb * a_bstride;
    const float* Bb = Bptr + (long long)(bb >> b_shift) * b_bhi
                           + (long long)(bb & b_bmask) * b_blo;
    float*       Cb = Cptr + (long long)(bb >> c_shift) * c_bhi
                           + (long long)(bb & c_bmask) * c_blo;

    float acc[8][8];
    #pragma unroll
    for (int i = 0; i < 8; i++)
        #pragma unroll
        for (int j = 0; j < 8; j++) acc[i][j] = 0.f;

    for (int k0 = 0; k0 < K; k0 += KC) {
        // ---- stage A tile: As[kk][m], 32 x 128 ----
        if (!AT) {
            // A is k-fast (a_kstride==1): vector-load along k, scatter into As
            #pragma unroll
            for (int it = 0; it < 4; it++) {
                int f4 = tid + it * 256;           // 0..1023 float4s
                int kq = f4 & 7;                   // k-quad
                int m  = f4 >> 3;                  // 0..127
                const float4 v = *(const float4*)(Ab + (long long)(m0 + m) * a_mstride
                                                     + (k0 + kq * 4));
                As[kq*4+0][m] = v.x; As[kq*4+1][m] = v.y;
                As[kq*4+2][m] = v.z; As[kq*4+3][m] = v.w;
            }
        } else {
            // A is m-fast (a_mstride==1): vector-load along m, store rows directly
            #pragma unroll
            for (int it = 0; it < 4; it++) {
                int f4 = tid + it * 256;
                int mq = f4 & 31;                  // m-quad (0..31)
                int kk = f4 >> 5;                  // 0..31
                *(float4*)&As[kk][mq*4] =
                    *(const float4*)(Ab + (m0 + mq * 4) + (long long)(k0 + kk) * a_kstride);
            }
        }
        // ---- stage B tile: Bs[kk][n], 32 x 128 ----
        if (!BT) {
            // B is n-fast (b_nstride==1)
            #pragma unroll
            for (int it = 0; it < 4; it++) {
                int f4 = tid + it * 256;
                int nq = f4 & 31;
                int kk = f4 >> 5;
                *(float4*)&Bs[kk][nq*4] =
                    *(const float4*)(Bb + (long long)(k0 + kk) * b_kstride + (n0 + nq * 4));
            }
        } else {
            // B is k-fast (b_kstride==1)
            #pragma unroll
            for (int it = 0; it < 4; it++) {
                int f4 = tid + it * 256;
                int kq = f4 & 7;
                int n  = f4 >> 3;
                const float4 v = *(const float4*)(Bb + (k0 + kq * 4)
                                                     + (long long)(n0 + n) * b_nstride);
                Bs[kq*4+0][n] = v.x; Bs[kq*4+1][n] = v.y;
                Bs[kq*4+2][n] = v.z; Bs[kq*4+3][n] = v.w;
            }
        }
        __syncthreads();

        #pragma unroll
        for (int kk = 0; kk < KC; kk++) {
            float4 a0 = *(const float4*)&As[kk][tr*8];
            float4 a1 = *(const float4*)&As[kk][tr*8+4];
            float4 b0 = *(const float4*)&Bs[kk][tc*8];
            float4 b1 = *(const float4*)&Bs[kk][tc*8+4];
            float av[8] = {a0.x,a0.y,a0.z,a0.w,a1.x,a1.y,a1.z,a1.w};
            float bv[8] = {b0.x,b0.y,b0.z,b0.w,b1.x,b1.y,b1.z,b1.w};
            #pragma unroll
            for (int i = 0; i < 8; i++)
                #pragma unroll
                for (int j = 0; j < 8; j++)
                    acc[i][j] = fmaf(av[i], bv[j], acc[i][j]);
        }
        __syncthreads();
    }

    if (SM) {
        // Row softmax over n (full row = 16 lanes x 8 values; lanes tr*16+tc,
        // the 16 lanes of a row group are consecutive within one wave).
        #pragma unroll
        for (int i = 0; i < 8; i++) {
            float mx = acc[i][0];
            #pragma unroll
            for (int j = 1; j < 8; j++) mx = fmaxf(mx, acc[i][j]);
            #pragma unroll
            for (int w = 1; w < 16; w <<= 1) mx = fmaxf(mx, __shfl_xor(mx, w, 64));
            float s = 0.f;
            #pragma unroll
            for (int j = 0; j < 8; j++) {
                float p = __expf(acc[i][j] - mx);
                acc[i][j] = p; s += p;
            }
            #pragma unroll
            for (int w = 1; w < 16; w <<= 1) s += __shfl_xor(s, w, 64);
            float rinv = 1.f / s;
            #pragma unroll
            for (int j = 0; j < 8; j++) acc[i][j] *= rinv;
        }
    }

    #pragma unroll
    for (int i = 0; i < 8; i++) {
        int m = m0 + tr * 8 + i;
        float bsum = (!SM && bias) ? bias[m] : 0.f;
        float* cp = Cb + (long long)m * c_mstride + (n0 + tc * 8);
        *(float4*)cp     = make_float4(acc[i][0]+bsum, acc[i][1]+bsum,
                                       acc[i][2]+bsum, acc[i][3]+bsum);
        *(float4*)(cp+4) = make_float4(acc[i][4]+bsum, acc[i][5]+bsum,
                                       acc[i][6]+bsum, acc[i][7]+bsum);
    }
}

extern "C" void kernel_launch(void* const* d_in, const int* in_sizes, int n_in,
                              void* d_out, int out_size, void* d_ws, size_t ws_size,
                              hipStream_t stream) {
    const float* x   = (const float*)d_in[0];
    const float* Wr  = (const float*)d_in[1];
    const float* br  = (const float*)d_in[2];
    const float* Wqw = (const float*)d_in[3];
    const float* bqw = (const float*)d_in[4];
    const float* Wkw = (const float*)d_in[5];
    const float* bkw = (const float*)d_in[6];
    const float* Wvw = (const float*)d_in[7];
    const float* bvw = (const float*)d_in[8];
    const float* Wqh = (const float*)d_in[9];
    const float* bqh = (const float*)d_in[10];
    const float* Wkh = (const float*)d_in[11];
    const float* bkh = (const float*)d_in[12];
    const float* Wvh = (const float*)d_in[13];
    const float* bvh = (const float*)d_in[14];
    const float* Wo  = (const float*)d_in[15];
    const float* bo  = (const float*)d_in[16];
    float* out = (float*)d_out;

    // 4 workspace slots of 8*128*128*128 floats (67MB each, 268MB total).
    // Liveness: A: resized -> P1 -> v2 ; B: q1 -> T1t -> P2 ;
    //           C: k1 -> q2 -> O2t    ; D: v1 -> k2.
    const long long SLOT = 16777216LL;
    float* ws = (float*)d_ws;
    float* A_ = ws;
    float* B_ = ws + SLOT;
    float* C_ = ws + 2 * SLOT;
    float* D_ = ws + 3 * SLOT;
    (void)in_sizes; (void)n_in; (void)out_size; (void)ws_size;

    dim3 blk(256);

    // 1) resize: resized[b][o][hw] = sum_c Wr[o][c] x[b][c][hw] + br  -> A_
    gemm_k<false,false,false><<<dim3(128,1,8), blk, 0, stream>>>(
        Wr, x, br, A_, 256,
        0LL, 256, 1,
        4194304LL, 0, 0, 0, 16384, 1,
        2097152LL, 0, 0, 0, 16384);

    // 2) q1/k1/v1: per (b,r): C[o][w] = sum_h W[o][h] resized[b,r,h,w] + bias
    //    stored natural [b][o][r][w]
    gemm_k<false,false,false><<<dim3(1,1,1024), blk, 0, stream>>>(
        Wqw, A_, bqw, B_, 128,
        0LL, 128, 1,
        16384LL, 0, 0, 0, 128, 1,
        2097152LL, 7, 127, 128, 16384);
    gemm_k<false,false,false><<<dim3(1,1,1024), blk, 0, stream>>>(
        Wkw, A_, bkw, C_, 128,
        0LL, 128, 1,
        16384LL, 0, 0, 0, 128, 1,
        2097152LL, 7, 127, 128, 16384);
    gemm_k<false,false,false><<<dim3(1,1,1024), blk, 0, stream>>>(
        Wvw, A_, bvw, D_, 128,
        0LL, 128, 1,
        16384LL, 0, 0, 0, 128, 1,
        2097152LL, 7, 127, 128, 16384);

    // 3) S1 + softmax: per (b,o): P[r][u] = softmax_u( sum_w q1[r,w] k1[u,w] ) -> A_
    gemm_k<false,true,true><<<dim3(1,1,1024), blk, 0, stream>>>(
        B_, C_, nullptr, A_, 128,
        16384LL, 128, 1,
        16384LL, 0, 0, 0, 1, 128,
        16384LL, 0, 0, 0, 128);

    // 4) PV1 (transposed): T1t[bo][w][r] = sum_u v1[u][w] P[r][u]  -> B_
    gemm_k<true,true,false><<<dim3(1,1,1024), blk, 0, stream>>>(
        D_, A_, nullptr, B_, 128,
        16384LL, 1, 128,
        16384LL, 0, 0, 0, 1, 128,
        16384LL, 0, 0, 0, 128);

    // 5) q2/k2/v2: per (b,h): C[o][r] = sum_w W[o][w] T1t[b,h,w,r] + bias
    //    stored k-major [b][o][h][r]
    gemm_k<false,false,false><<<dim3(1,1,1024), blk, 0, stream>>>(
        Wqh, B_, bqh, C_, 128,
        0LL, 128, 1,
        16384LL, 0, 0, 0, 128, 1,
        2097152LL, 7, 127, 128, 16384);
    gemm_k<false,false,false><<<dim3(1,1,1024), blk, 0, stream>>>(
        Wkh, B_, bkh, D_, 128,
        0LL, 128, 1,
        16384LL, 0, 0, 0, 128, 1,
        2097152LL, 7, 127, 128, 16384);
    gemm_k<false,false,false><<<dim3(1,1,1024), blk, 0, stream>>>(
        Wvh, B_, bvh, A_, 128,
        0LL, 128, 1,
        16384LL, 0, 0, 0, 128, 1,
        2097152LL, 7, 127, 128, 16384);

    // 6) S2 + softmax: per (b,o): P2[r][u] = softmax_u( sum_h q2[r,h] k2[u,h] ) -> B_
    //    q2 is m-fast (Q2t[h][r]), k2 is n-fast (K2t[h][u])
    gemm_k<true,false,true><<<dim3(1,1,1024), blk, 0, stream>>>(
        C_, D_, nullptr, B_, 128,
        16384LL, 1, 128,
        16384LL, 0, 0, 0, 128, 1,
        16384LL, 0, 0, 0, 128);

    // 7) PV2 (transposed): O2t[bo][h][r] = sum_u v2t[h][u] P2[r][u] -> C_
    gemm_k<false,true,false><<<dim3(1,1,1024), blk, 0, stream>>>(
        A_, B_, nullptr, C_, 128,
        16384LL, 128, 1,
        16384LL, 0, 0, 0, 1, 128,
        16384LL, 0, 0, 0, 128);

    // 8) restore: per (b,h): out[b][co][h][w] = sum_r Wo[co][r] O2t[b,w,h,r] + bo
    gemm_k<false,true,false><<<dim3(1,2,1024), blk, 0, stream>>>(
        Wo, C_, bo, out, 128,
        0LL, 128, 1,
        2097152LL, 7, 127, 128, 1, 16384,
        4194304LL, 7, 127, 128, 16384);
}

// Round 2
// 334.841 us; speedup vs baseline: 2.5461x; 2.5461x over previous
//
#include <hip/hip_runtime.h>
#include <hip/hip_bf16.h>

// CSAA on MFMA: resize -> width axial attn -> height axial attn -> restore.
// B=8, CIN=256, COUT=256, R=H=W=128. All intermediates bf16, fp32 accum.
//
// Pass graph (all GEMM stagings are DIRECT k-fast; zero transpose staging):
//  T0 : xt[b][hw][c]        = bf16(x[b][c][hw])            (LDS-tile transpose)
//  K1 : resized_t[b][r][w][h] per (b,w):  M=r,N=h,K=c(256)  A=Wr    B=xt
//  K2a: q1,k1[b][o][r][w]    per (b,r):   M=o,N=w,K=h       A=Wq/Wk B=resized_t
//  K2b: v1t[b][o][w][u]      per (b,w):   M=o,N=u,K=h       A=Wv    B=resized_t
//  K3 : out1[b][o][r][w]     per (b,o):   flash attn (S=QK^T, softmax, PV)
//  K4a: q2t,k2t[b][o2][c][h'] per (b,c):  M=o2,N=h',K=w     A=Wqh/Wkh B=out1
//  K4b: v2t[b][o2][h'][c]    per (b,h'):  M=o2,N=c,K=w      A=Wvh   B=out1
//  K5 : out2st[b][o2][h'][c] per (b,o2):  flash attn, transposed epilogue
//  K6 : out[b][co][h'][o2]   per (b,h')x2: M=co(256),N=o2,K=c  A=Wo  B=out2st (fp32 out)

typedef __attribute__((ext_vector_type(8))) short bf16x8;
typedef __attribute__((ext_vector_type(4))) float f32x4;
typedef __attribute__((ext_vector_type(4))) short short4v;

__device__ __forceinline__ short f2b(float f) {
    __hip_bfloat16 h = __float2bfloat16(f);
    short s; __builtin_memcpy(&s, &h, 2);
    return s;
}

// XOR-swizzled LDS addressing: 128 rows x 128 bf16, 16B-block index swizzle.
// Returns element offset of 16B block `blk` (0..15) in row `row` (0..127).
__device__ __forceinline__ int swzb(int row, int blk) {
    return (row << 7) + ((blk ^ (row & 7)) << 3);
}

// 128x128x128 wave-tiled MFMA GEMM: 4 waves, each 32(m) x 128(n).
// A-frag row = lane&15 (+16*mi), B-frag col = lane&15, k = (kk*4+(lane>>4))*8..+7.
__device__ __forceinline__ void mfma_gemm(const short* SA, const short* SB,
                                          f32x4 (&acc)[2][8], int lane, int w32) {
    #pragma unroll
    for (int kk = 0; kk < 4; kk++) {
        const int kb = kk * 4 + (lane >> 4);
        bf16x8 a0 = *(const bf16x8*)&SA[swzb(w32 + (lane & 15), kb)];
        bf16x8 a1 = *(const bf16x8*)&SA[swzb(w32 + 16 + (lane & 15), kb)];
        #pragma unroll
        for (int ni = 0; ni < 8; ni++) {
            bf16x8 bv = *(const bf16x8*)&SB[swzb(ni * 16 + (lane & 15), kb)];
            acc[0][ni] = __builtin_amdgcn_mfma_f32_16x16x32_bf16(a0, bv, acc[0][ni], 0, 0, 0);
            acc[1][ni] = __builtin_amdgcn_mfma_f32_16x16x32_bf16(a1, bv, acc[1][ni], 0, 0, 0);
        }
    }
}

// ---------------- T0: transpose+convert x ----------------
__global__ __launch_bounds__(256)
void xpose(const float* __restrict__ x, short* __restrict__ xt) {
    __shared__ short tile[64][80];          // 80: keeps 16B row alignment
    const int t = threadIdx.x;
    const int hw0 = blockIdx.x * 64;
    const int c0  = blockIdx.y * 64;
    const long long bo = (long long)blockIdx.z * 4194304LL;
    const float* xb = x + bo;
    short* xtb = xt + bo;
    #pragma unroll
    for (int i = 0; i < 4; i++) {
        int cc = (t >> 4) + i * 16;
        int hw = (t & 15) * 4;
        float4 v = *(const float4*)(xb + (long long)(c0 + cc) * 16384 + hw0 + hw);
        tile[hw + 0][cc] = f2b(v.x);
        tile[hw + 1][cc] = f2b(v.y);
        tile[hw + 2][cc] = f2b(v.z);
        tile[hw + 3][cc] = f2b(v.w);
    }
    __syncthreads();
    #pragma unroll
    for (int i = 0; i < 2; i++) {
        int idx = t + i * 256;
        int row = idx >> 3, ch = idx & 7;
        *(bf16x8*)(xtb + (long long)(hw0 + row) * 256 + c0 + ch * 8) =
            *(const bf16x8*)&tile[row][ch * 8];
    }
}

// ---------------- generic weight-GEMM ----------------
// NW weight matrices (fp32, [m][k] k-fast) against one shared bf16 B panel.
// B row n: Bsrc + bz*b_z + bx*b_x + n*b_r + k. C row m: + m*c_m + n (bf16),
// or fp32 direct store when F32OUT.
template<int NW, int KSTEPS, bool F32OUT>
__global__ __launch_bounds__(256)
void gemmw(const float* __restrict__ W0, const float* __restrict__ W1,
           const float* __restrict__ bias0, const float* __restrict__ bias1,
           const short* __restrict__ Bsrc, long long b_z, long long b_x, long long b_r,
           short* __restrict__ C0, short* __restrict__ C1, float* __restrict__ Cf,
           long long c_z, long long c_x, long long c_m) {
    __shared__ short As[128 * 128];
    __shared__ short Bs[128 * 128];
    const int t = threadIdx.x;
    const int lane = t & 63;
    const int w32 = (t >> 6) * 32;
    const int bx = blockIdx.x, my = blockIdx.y, bz = blockIdx.z;
    const int Krow = 128 * KSTEPS;

    const short* Bb = Bsrc + bz * b_z + bx * b_x;

    f32x4 acc[NW][2][8];
    #pragma unroll
    for (int g = 0; g < NW; g++)
        #pragma unroll
        for (int mi = 0; mi < 2; mi++)
            #pragma unroll
            for (int ni = 0; ni < 8; ni++)
                acc[g][mi][ni] = (f32x4){0.f, 0.f, 0.f, 0.f};

    for (int ks = 0; ks < KSTEPS; ks++) {
        // stage B tile (128 rows, k-fast, bf16 direct)
        #pragma unroll
        for (int i = 0; i < 8; i++) {
            int idx = t + i * 256;
            int row = idx >> 4, ch = idx & 15;
            bf16x8 v = *(const bf16x8*)(Bb + (long long)row * b_r + ks * 128 + ch * 8);
            *(bf16x8*)&Bs[swzb(row, ch)] = v;
        }
        #pragma unroll
        for (int g = 0; g < NW; g++) {
            const float* W = (g == 0) ? W0 : W1;
            // stage A tile (fp32 -> bf16)
            #pragma unroll
            for (int i = 0; i < 16; i++) {
                int idx = t + i * 256;
                int row = idx >> 5, c4 = idx & 31;
                float4 v = *(const float4*)(W + (long long)(my * 128 + row) * Krow + ks * 128 + c4 * 4);
                short4v s4 = { f2b(v.x), f2b(v.y), f2b(v.z), f2b(v.w) };
                *(short4v*)&As[swzb(row, c4 >> 1) + (c4 & 1) * 4] = s4;
            }
            __syncthreads();
            mfma_gemm(As, Bs, acc[g], lane, w32);
            __syncthreads();
        }
    }

    if (F32OUT) {
        float* Cb = Cf + bz * c_z + bx * c_x;
        #pragma unroll
        for (int mi = 0; mi < 2; mi++)
            #pragma unroll
            for (int r = 0; r < 4; r++) {
                int row = my * 128 + w32 + mi * 16 + (lane >> 4) * 4 + r;
                float bb = bias0[row];
                #pragma unroll
                for (int ni = 0; ni < 8; ni++) {
                    int col = ni * 16 + (lane & 15);
                    Cb[(long long)row * c_m + col] = acc[0][mi][ni][r] + bb;
                }
            }
    } else {
        #pragma unroll
        for (int g = 0; g < NW; g++) {
            const float* bias = (g == 0) ? bias0 : bias1;
            // bounce acc[g] -> As as [m][n] bf16, then coalesced b128 stores
            #pragma unroll
            for (int mi = 0; mi < 2; mi++)
                #pragma unroll
                for (int r = 0; r < 4; r++) {
                    int row = w32 + mi * 16 + (lane >> 4) * 4 + r;
                    float bb = bias[row];
                    #pragma unroll
                    for (int ni = 0; ni < 8; ni++) {
                        int col = ni * 16 + (lane & 15);
                        As[swzb(row, col >> 3) + (col & 7)] = f2b(acc[g][mi][ni][r] + bb);
                    }
                }
            __syncthreads();
            short* Cg = ((g == 0) ? C0 : C1) + bz * c_z + bx * c_x;
            #pragma unroll
            for (int i = 0; i < 8; i++) {
                int idx = t + i * 256;
                int row = idx >> 4, ch = idx & 15;
                bf16x8 v = *(const bf16x8*)&As[swzb(row, ch)];
                *(bf16x8*)(Cg + (long long)row * c_m + ch * 8) = v;
            }
            __syncthreads();
        }
    }
}

// ---------------- fused attention per (b,o) ----------------
// Q,K,V panels: 128 rows, stride 128, k-fast. S=QK^T (contracts k-fast dim),
// in-register wave softmax over n, P->LDS (own rows), PV with V staged direct.
// TEPI: write output transposed ([n][m]) for the restore pass.
template<bool TEPI>
__global__ __launch_bounds__(256)
void attnk(const short* __restrict__ Q, const short* __restrict__ Kp,
           const short* __restrict__ V, short* __restrict__ O) {
    __shared__ short SA[128 * 128];
    __shared__ short SB[128 * 128];
    const int t = threadIdx.x;
    const int lane = t & 63;
    const int w32 = (t >> 6) * 32;
    const long long poff = (long long)blockIdx.z * 2097152LL + (long long)blockIdx.x * 16384LL;
    const short* Qb = Q + poff;
    const short* Kb = Kp + poff;
    const short* Vb = V + poff;
    short* Ob = O + poff;

    #pragma unroll
    for (int i = 0; i < 8; i++) {
        int idx = t + i * 256;
        int row = idx >> 4, ch = idx & 15;
        *(bf16x8*)&SA[swzb(row, ch)] = *(const bf16x8*)(Qb + row * 128 + ch * 8);
        *(bf16x8*)&SB[swzb(row, ch)] = *(const bf16x8*)(Kb + row * 128 + ch * 8);
    }
    __syncthreads();

    f32x4 acc[2][8];
    #pragma unroll
    for (int mi = 0; mi < 2; mi++)
        #pragma unroll
        for (int ni = 0; ni < 8; ni++) acc[mi][ni] = (f32x4){0.f, 0.f, 0.f, 0.f};
    mfma_gemm(SA, SB, acc, lane, w32);

    // in-register softmax over n (row = 16 lanes x 8 frags; xor-shuffle stays in quad-group)
    #pragma unroll
    for (int mi = 0; mi < 2; mi++)
        #pragma unroll
        for (int r = 0; r < 4; r++) {
            float mx = acc[mi][0][r];
            #pragma unroll
            for (int ni = 1; ni < 8; ni++) mx = fmaxf(mx, acc[mi][ni][r]);
            #pragma unroll
            for (int d = 1; d < 16; d <<= 1) mx = fmaxf(mx, __shfl_xor(mx, d, 64));
            float s = 0.f;
            #pragma unroll
            for (int ni = 0; ni < 8; ni++) {
                float p = __expf(acc[mi][ni][r] - mx);
                acc[mi][ni][r] = p;
                s += p;
            }
            #pragma unroll
            for (int d = 1; d < 16; d <<= 1) s += __shfl_xor(s, d, 64);
            float rinv = 1.f / s;
            #pragma unroll
            for (int ni = 0; ni < 8; ni++) acc[mi][ni][r] *= rinv;
        }

    __syncthreads();   // all waves done reading Q/K panels

    // P -> SA (each wave its own 32 rows), V -> SB (cooperative)
    #pragma unroll
    for (int mi = 0; mi < 2; mi++)
        #pragma unroll
        for (int r = 0; r < 4; r++) {
            int row = w32 + mi * 16 + (lane >> 4) * 4 + r;
            #pragma unroll
            for (int ni = 0; ni < 8; ni++) {
                int col = ni * 16 + (lane & 15);
                SA[swzb(row, col >> 3) + (col & 7)] = f2b(acc[mi][ni][r]);
            }
        }
    #pragma unroll
    for (int i = 0; i < 8; i++) {
        int idx = t + i * 256;
        int row = idx >> 4, ch = idx & 15;
        *(bf16x8*)&SB[swzb(row, ch)] = *(const bf16x8*)(Vb + row * 128 + ch * 8);
    }
    __syncthreads();

    f32x4 acc2[2][8];
    #pragma unroll
    for (int mi = 0; mi < 2; mi++)
        #pragma unroll
        for (int ni = 0; ni < 8; ni++) acc2[mi][ni] = (f32x4){0.f, 0.f, 0.f, 0.f};
    mfma_gemm(SA, SB, acc2, lane, w32);
    __syncthreads();   // done reading SB before bounce overwrite

    #pragma unroll
    for (int mi = 0; mi < 2; mi++)
        #pragma unroll
        for (int r = 0; r < 4; r++) {
            int row = w32 + mi * 16 + (lane >> 4) * 4 + r;
            #pragma unroll
            for (int ni = 0; ni < 8; ni++) {
                int col = ni * 16 + (lane & 15);
                short vv = f2b(acc2[mi][ni][r]);
                if (!TEPI) SB[swzb(row, col >> 3) + (col & 7)] = vv;
                else       SB[swzb(col, row >> 3) + (row & 7)] = vv;
            }
        }
    __syncthreads();
    #pragma unroll
    for (int i = 0; i < 8; i++) {
        int idx = t + i * 256;
        int row = idx >> 4, ch = idx & 15;
        *(bf16x8*)(Ob + row * 128 + ch * 8) = *(const bf16x8*)&SB[swzb(row, ch)];
    }
}

extern "C" void kernel_launch(void* const* d_in, const int* in_sizes, int n_in,
                              void* d_out, int out_size, void* d_ws, size_t ws_size,
                              hipStream_t stream) {
    const float* x   = (const float*)d_in[0];
    const float* Wr  = (const float*)d_in[1];
    const float* br  = (const float*)d_in[2];
    const float* Wqw = (const float*)d_in[3];
    const float* bqw = (const float*)d_in[4];
    const float* Wkw = (const float*)d_in[5];
    const float* bkw = (const float*)d_in[6];
    const float* Wvw = (const float*)d_in[7];
    const float* bvw = (const float*)d_in[8];
    const float* Wqh = (const float*)d_in[9];
    const float* bqh = (const float*)d_in[10];
    const float* Wkh = (const float*)d_in[11];
    const float* bkh = (const float*)d_in[12];
    const float* Wvh = (const float*)d_in[13];
    const float* bvh = (const float*)d_in[14];
    const float* Wo  = (const float*)d_in[15];
    const float* bo  = (const float*)d_in[16];
    float* out = (float*)d_out;
    (void)in_sizes; (void)n_in; (void)out_size; (void)ws_size;

    // bf16 workspace slots, U = 8*128^3 elems (33.5MB). Liveness-packed: 7U total.
    const long long U = 16777216LL;
    short* ws  = (short*)d_ws;
    short* xt  = ws;            // [0,2U)  x transposed (dead after K1)
    short* rsz = ws + 2 * U;    // resized_t (dead after K2b)
    short* q1  = ws + 3 * U;    // dead after K3
    short* k1  = ws + 4 * U;    // dead after K3
    short* v1  = ws + 5 * U;    // dead after K3
    short* o1  = ws + 6 * U;    // dead after K4b
    short* q2  = ws;            // reuse xt space
    short* k2  = ws + U;
    short* v2  = ws + 2 * U;    // reuse rsz
    short* o2  = ws + 3 * U;    // reuse q1

    dim3 blk(256);

    xpose<<<dim3(256, 4, 8), blk, 0, stream>>>(x, xt);

    // K1: resized_t[b][r][w][h], per (b,w); K=256
    gemmw<1, 2, false><<<dim3(128, 1, 8), blk, 0, stream>>>(
        Wr, nullptr, br, nullptr,
        xt, 4194304LL, 256LL, 32768LL,
        rsz, nullptr, nullptr, 2097152LL, 128LL, 16384LL);

    // K2a: q1,k1[b][o][r][w], per (b,r)
    gemmw<2, 1, false><<<dim3(128, 1, 8), blk, 0, stream>>>(
        Wqw, Wkw, bqw, bkw,
        rsz, 2097152LL, 16384LL, 128LL,
        q1, k1, nullptr, 2097152LL, 128LL, 16384LL);

    // K2b: v1t[b][o][w][u], per (b,w)
    gemmw<1, 1, false><<<dim3(128, 1, 8), blk, 0, stream>>>(
        Wvw, nullptr, bvw, nullptr,
        rsz, 2097152LL, 128LL, 16384LL,
        v1, nullptr, nullptr, 2097152LL, 128LL, 16384LL);

    // K3: width attention -> out1[b][o][r][w]
    attnk<false><<<dim3(128, 1, 8), blk, 0, stream>>>(q1, k1, v1, o1);

    // K4a: q2t,k2t[b][o2][c][h'], per (b,c)
    gemmw<2, 1, false><<<dim3(128, 1, 8), blk, 0, stream>>>(
        Wqh, Wkh, bqh, bkh,
        o1, 2097152LL, 128LL, 16384LL,
        q2, k2, nullptr, 2097152LL, 128LL, 16384LL);

    // K4b: v2t[b][o2][h'][c], per (b,h')
    gemmw<1, 1, false><<<dim3(128, 1, 8), blk, 0, stream>>>(
        Wvh, nullptr, bvh, nullptr,
        o1, 2097152LL, 16384LL, 128LL,
        v2, nullptr, nullptr, 2097152LL, 128LL, 16384LL);

    // K5: height attention -> out2st[b][o2][h'][c] (transposed epilogue)
    attnk<true><<<dim3(128, 1, 8), blk, 0, stream>>>(q2, k2, v2, o2);

    // K6: restore -> out[b][co][h'][o2] fp32, per (b,h'), 2 m-tiles
    gemmw<1, 1, true><<<dim3(128, 2, 8), blk, 0, stream>>>(
        Wo, nullptr, bo, nullptr,
        o2, 2097152LL, 128LL, 16384LL,
        nullptr, nullptr, out, 4194304LL, 128LL, 16384LL);
}

// Round 3
// 292.465 us; speedup vs baseline: 2.9151x; 1.1449x over previous
//
#include <hip/hip_runtime.h>
#include <hip/hip_bf16.h>

// CSAA on MFMA, round 3: bf16 pre-swizzled weight images (wprep), 64x64 wave
// tiles, global_load_lds staging (linear LDS dest + inverse-swizzled source).
// Pass structure identical to round 2 (verified offsets preserved verbatim).

typedef __attribute__((ext_vector_type(8))) short bf16x8;
typedef __attribute__((ext_vector_type(4))) float f32x4;

__device__ __forceinline__ short f2b(float f) {
    __hip_bfloat16 h = __float2bfloat16(f);
    short s; __builtin_memcpy(&s, &h, 2);
    return s;
}

// XOR-swizzled LDS addressing: 128 rows x 128 bf16; 16B-block index swizzle.
__device__ __forceinline__ int swzb(int row, int blk) {
    return (row << 7) + ((blk ^ (row & 7)) << 3);
}

// async global->LDS, 16B per lane. LDS dest must be wave-uniform base
// (HW writes base + lane*16); global src is per-lane.
__device__ __forceinline__ void gload16(const void* g, void* l) {
    __builtin_amdgcn_global_load_lds(
        (const __attribute__((address_space(1))) void*)g,
        (__attribute__((address_space(3))) void*)l, 16, 0, 0);
}

// 64x64 wave tile over 128x128x128: per kk: 4 A-frags + 4 B-frags, 16 MFMA.
__device__ __forceinline__ void mfma64(const short* __restrict__ SA,
                                       const short* __restrict__ SB,
                                       f32x4 (&acc)[4][4], int lane,
                                       int wr64, int wc64) {
    #pragma unroll
    for (int kk = 0; kk < 4; kk++) {
        const int kb = kk * 4 + (lane >> 4);
        bf16x8 a[4], b[4];
        #pragma unroll
        for (int mi = 0; mi < 4; mi++)
            a[mi] = *(const bf16x8*)&SA[swzb(wr64 + mi * 16 + (lane & 15), kb)];
        #pragma unroll
        for (int ni = 0; ni < 4; ni++)
            b[ni] = *(const bf16x8*)&SB[swzb(wc64 + ni * 16 + (lane & 15), kb)];
        #pragma unroll
        for (int mi = 0; mi < 4; mi++)
            #pragma unroll
            for (int ni = 0; ni < 4; ni++)
                acc[mi][ni] = __builtin_amdgcn_mfma_f32_16x16x32_bf16(
                    a[mi], b[ni], acc[mi][ni], 0, 0, 0);
    }
}

// ---------------- wprep: fp32 weights -> bf16 pre-swizzled LDS images --------
// Image layout per weight: [my][ks][row 0..127][16B-blk swizzled]; loading it
// LINEARLY into LDS and reading with swzb() yields W[row][k].
__global__ __launch_bounds__(256)
void wprep(const float* __restrict__ Wr, const float* __restrict__ Wqw,
           const float* __restrict__ Wkw, const float* __restrict__ Wvw,
           const float* __restrict__ Wqh, const float* __restrict__ Wkh,
           const float* __restrict__ Wvh, const float* __restrict__ Wo,
           short* __restrict__ dst) {
    const int id = blockIdx.y;
    const float* W; int M, K, off;
    switch (id) {
        case 0: W = Wr;  M = 128; K = 256; off = 0;      break;
        case 1: W = Wqw; M = 128; K = 128; off = 32768;  break;
        case 2: W = Wkw; M = 128; K = 128; off = 49152;  break;
        case 3: W = Wvw; M = 128; K = 128; off = 65536;  break;
        case 4: W = Wqh; M = 128; K = 128; off = 81920;  break;
        case 5: W = Wkh; M = 128; K = 128; off = 98304;  break;
        case 6: W = Wvh; M = 128; K = 128; off = 114688; break;
        default: W = Wo; M = 256; K = 128; off = 131072; break;
    }
    int g = blockIdx.x * 256 + threadIdx.x;      // 16B-group index
    if (g >= (M * K) >> 3) return;
    int gpr = K >> 3;                            // groups per row
    int row = g / gpr;
    int blk = g - row * gpr;
    int ks = blk >> 4, bi = blk & 15;
    int my = row >> 7, r = row & 127;
    int nks = K >> 7;
    const float* s = W + (long long)row * K + blk * 8;
    float4 v0 = *(const float4*)s, v1 = *(const float4*)(s + 4);
    bf16x8 ov;
    ov[0] = f2b(v0.x); ov[1] = f2b(v0.y); ov[2] = f2b(v0.z); ov[3] = f2b(v0.w);
    ov[4] = f2b(v1.x); ov[5] = f2b(v1.y); ov[6] = f2b(v1.z); ov[7] = f2b(v1.w);
    *(bf16x8*)(dst + off + (my * nks + ks) * 16384 + swzb(r, bi)) = ov;
}

// ---------------- T0: transpose+convert x ----------------
__global__ __launch_bounds__(256)
void xpose(const float* __restrict__ x, short* __restrict__ xt) {
    __shared__ short tile[64][80];
    const int t = threadIdx.x;
    const int hw0 = blockIdx.x * 64;
    const int c0  = blockIdx.y * 64;
    const long long bo = (long long)blockIdx.z * 4194304LL;
    const float* xb = x + bo;
    short* xtb = xt + bo;
    #pragma unroll
    for (int i = 0; i < 4; i++) {
        int cc = (t >> 4) + i * 16;
        int hw = (t & 15) * 4;
        float4 v = *(const float4*)(xb + (long long)(c0 + cc) * 16384 + hw0 + hw);
        tile[hw + 0][cc] = f2b(v.x);
        tile[hw + 1][cc] = f2b(v.y);
        tile[hw + 2][cc] = f2b(v.z);
        tile[hw + 3][cc] = f2b(v.w);
    }
    __syncthreads();
    #pragma unroll
    for (int i = 0; i < 2; i++) {
        int idx = t + i * 256;
        int row = idx >> 3, ch = idx & 7;
        *(bf16x8*)(xtb + (long long)(hw0 + row) * 256 + c0 + ch * 8) =
            *(const bf16x8*)&tile[row][ch * 8];
    }
}

// ---------------- weight-GEMM (A = pre-swizzled bf16 image) ----------------
template<int NW, int KSTEPS, bool F32OUT>
__global__ __launch_bounds__(256)
void gemmw(const short* __restrict__ A0, const short* __restrict__ A1,
           const float* __restrict__ bias0, const float* __restrict__ bias1,
           const short* __restrict__ Bsrc, long long b_z, long long b_x, long long b_r,
           short* __restrict__ C0, short* __restrict__ C1, float* __restrict__ Cf,
           long long c_z, long long c_x, long long c_m) {
    __shared__ short As[16384];
    __shared__ short Bs[16384];
    const int t = threadIdx.x;
    const int lane = t & 63;
    const int wid = t >> 6;
    const int wr64 = (wid >> 1) * 64, wc64 = (wid & 1) * 64;
    const int bx = blockIdx.x, my = blockIdx.y, bz = blockIdx.z;
    const short* Bb = Bsrc + bz * b_z + bx * b_x;

    f32x4 acc[NW][4][4];
    #pragma unroll
    for (int g = 0; g < NW; g++)
        #pragma unroll
        for (int mi = 0; mi < 4; mi++)
            #pragma unroll
            for (int ni = 0; ni < 4; ni++)
                acc[g][mi][ni] = (f32x4){0.f, 0.f, 0.f, 0.f};

    for (int ks = 0; ks < KSTEPS; ks++) {
        // stage B: per-lane inverse-swizzled source, linear LDS dest
        #pragma unroll
        for (int i = 0; i < 8; i++) {
            int q = wid * 8 + i;
            int row = q * 4 + (lane >> 4);
            gload16(Bb + (long long)row * b_r + ks * 128
                       + (((lane & 15) ^ (row & 7)) << 3), &Bs[q * 512]);
        }
        #pragma unroll
        for (int g = 0; g < NW; g++) {
            const short* Ai = ((g == 0) ? A0 : A1) + (my * KSTEPS + ks) * 16384;
            #pragma unroll
            for (int i = 0; i < 8; i++) {
                int q = wid * 8 + i;
                gload16(Ai + q * 512 + lane * 8, &As[q * 512]);
            }
            __syncthreads();
            mfma64(As, Bs, acc[g], lane, wr64, wc64);
            __syncthreads();
        }
    }

    if (F32OUT) {
        float* Cb = Cf + bz * c_z + bx * c_x;
        #pragma unroll
        for (int mi = 0; mi < 4; mi++)
            #pragma unroll
            for (int r = 0; r < 4; r++) {
                int rl = wr64 + mi * 16 + (lane >> 4) * 4 + r;
                int row = my * 128 + rl;
                float bb = bias0[row];
                #pragma unroll
                for (int ni = 0; ni < 4; ni++) {
                    int col = wc64 + ni * 16 + (lane & 15);
                    Cb[(long long)row * c_m + col] = acc[0][mi][ni][r] + bb;
                }
            }
    } else {
        #pragma unroll
        for (int g = 0; g < NW; g++) {
            const float* bias = (g == 0) ? bias0 : bias1;
            #pragma unroll
            for (int mi = 0; mi < 4; mi++)
                #pragma unroll
                for (int r = 0; r < 4; r++) {
                    int row = wr64 + mi * 16 + (lane >> 4) * 4 + r;
                    float bb = bias[row];
                    #pragma unroll
                    for (int ni = 0; ni < 4; ni++) {
                        int col = wc64 + ni * 16 + (lane & 15);
                        As[swzb(row, col >> 3) + (col & 7)] = f2b(acc[g][mi][ni][r] + bb);
                    }
                }
            __syncthreads();
            short* Cg = ((g == 0) ? C0 : C1) + bz * c_z + bx * c_x;
            #pragma unroll
            for (int i = 0; i < 8; i++) {
                int idx = t + i * 256;
                int row = idx >> 4, ch = idx & 15;
                *(bf16x8*)(Cg + (long long)row * c_m + ch * 8) =
                    *(const bf16x8*)&As[swzb(row, ch)];
            }
            __syncthreads();
        }
    }
}

// ---------------- fused attention per (b,o), 64x64 waves ----------------
// Split-row softmax: each row spans 2 waves (wc half); partials merged in LDS.
// P stored UNSCALED (exp(x - rowmax)); 1/rowsum folded into the PV epilogue.
template<bool TEPI>
__global__ __launch_bounds__(256)
void attnk(const short* __restrict__ Q, const short* __restrict__ Kp,
           const short* __restrict__ V, short* __restrict__ O) {
    __shared__ short SA[16384];
    __shared__ short SB[16384];
    __shared__ float pmax[2][128];
    __shared__ float psum[2][128];
    const int t = threadIdx.x;
    const int lane = t & 63;
    const int wid = t >> 6;
    const int wr64 = (wid >> 1) * 64, wc64 = (wid & 1) * 64, wch = wid & 1;
    const long long poff = (long long)blockIdx.z * 2097152LL
                         + (long long)blockIdx.x * 16384LL;
    const short* Qb = Q + poff;
    const short* Kb = Kp + poff;
    const short* Vb = V + poff;
    short* Ob = O + poff;

    #pragma unroll
    for (int i = 0; i < 8; i++) {
        int q = wid * 8 + i;
        int row = q * 4 + (lane >> 4);
        int sw = ((lane & 15) ^ (row & 7)) << 3;
        gload16(Qb + row * 128 + sw, &SA[q * 512]);
        gload16(Kb + row * 128 + sw, &SB[q * 512]);
    }
    __syncthreads();

    f32x4 acc[4][4];
    #pragma unroll
    for (int mi = 0; mi < 4; mi++)
        #pragma unroll
        for (int ni = 0; ni < 4; ni++) acc[mi][ni] = (f32x4){0.f, 0.f, 0.f, 0.f};
    mfma64(SA, SB, acc, lane, wr64, wc64);

    // wave-partial row max (over this wave's 64 cols)
    #pragma unroll
    for (int mi = 0; mi < 4; mi++)
        #pragma unroll
        for (int r = 0; r < 4; r++) {
            float mx = fmaxf(fmaxf(acc[mi][0][r], acc[mi][1][r]),
                             fmaxf(acc[mi][2][r], acc[mi][3][r]));
            #pragma unroll
            for (int d = 1; d < 16; d <<= 1) mx = fmaxf(mx, __shfl_xor(mx, d, 64));
            if ((lane & 15) == 0)
                pmax[wch][wr64 + mi * 16 + (lane >> 4) * 4 + r] = mx;
        }
    __syncthreads();   // bar1: maxes visible; SA/SB reads complete

    // stage V early (async, dest SB is free after bar1)
    #pragma unroll
    for (int i = 0; i < 8; i++) {
        int q = wid * 8 + i;
        int row = q * 4 + (lane >> 4);
        gload16(Vb + row * 128 + (((lane & 15) ^ (row & 7)) << 3), &SB[q * 512]);
    }
    // exp (unscaled), partial sums, scatter P -> SA
    #pragma unroll
    for (int mi = 0; mi < 4; mi++)
        #pragma unroll
        for (int r = 0; r < 4; r++) {
            int row = wr64 + mi * 16 + (lane >> 4) * 4 + r;
            float M = fmaxf(pmax[0][row], pmax[1][row]);
            float p[4], s = 0.f;
            #pragma unroll
            for (int ni = 0; ni < 4; ni++) {
                p[ni] = __expf(acc[mi][ni][r] - M);
                s += p[ni];
            }
            #pragma unroll
            for (int d = 1; d < 16; d <<= 1) s += __shfl_xor(s, d, 64);
            if ((lane & 15) == 0) psum[wch][row] = s;
            #pragma unroll
            for (int ni = 0; ni < 4; ni++) {
                int col = wc64 + ni * 16 + (lane & 15);
                SA[swzb(row, col >> 3) + (col & 7)] = f2b(p[ni]);
            }
        }
    __syncthreads();   // bar2: V in SB, P in SA, psum visible

    f32x4 acc2[4][4];
    #pragma unroll
    for (int mi = 0; mi < 4; mi++)
        #pragma unroll
        for (int ni = 0; ni < 4; ni++) acc2[mi][ni] = (f32x4){0.f, 0.f, 0.f, 0.f};
    mfma64(SA, SB, acc2, lane, wr64, wc64);
    __syncthreads();   // bar3: SB free for output bounce

    #pragma unroll
    for (int mi = 0; mi < 4; mi++)
        #pragma unroll
        for (int r = 0; r < 4; r++) {
            int row = wr64 + mi * 16 + (lane >> 4) * 4 + r;
            float rinv = 1.f / (psum[0][row] + psum[1][row]);
            #pragma unroll
            for (int ni = 0; ni < 4; ni++) {
                int col = wc64 + ni * 16 + (lane & 15);
                short vv = f2b(acc2[mi][ni][r] * rinv);
                if (!TEPI) SB[swzb(row, col >> 3) + (col & 7)] = vv;
                else       SB[swzb(col, row >> 3) + (row & 7)] = vv;
            }
        }
    __syncthreads();
    #pragma unroll
    for (int i = 0; i < 8; i++) {
        int idx = t + i * 256;
        int row = idx >> 4, ch = idx & 15;
        *(bf16x8*)(Ob + row * 128 + ch * 8) = *(const bf16x8*)&SB[swzb(row, ch)];
    }
}

extern "C" void kernel_launch(void* const* d_in, const int* in_sizes, int n_in,
                              void* d_out, int out_size, void* d_ws, size_t ws_size,
                              hipStream_t stream) {
    const float* x   = (const float*)d_in[0];
    const float* Wr  = (const float*)d_in[1];
    const float* br  = (const float*)d_in[2];
    const float* Wqw = (const float*)d_in[3];
    const float* bqw = (const float*)d_in[4];
    const float* Wkw = (const float*)d_in[5];
    const float* bkw = (const float*)d_in[6];
    const float* Wvw = (const float*)d_in[7];
    const float* bvw = (const float*)d_in[8];
    const float* Wqh = (const float*)d_in[9];
    const float* bqh = (const float*)d_in[10];
    const float* Wkh = (const float*)d_in[11];
    const float* bkh = (const float*)d_in[12];
    const float* Wvh = (const float*)d_in[13];
    const float* bvh = (const float*)d_in[14];
    const float* Wo  = (const float*)d_in[15];
    const float* bo  = (const float*)d_in[16];
    float* out = (float*)d_out;
    (void)in_sizes; (void)n_in; (void)out_size; (void)ws_size;

    // bf16 workspace slots, U = 8*128^3 elems (33.5MB). 7U tensors + weights.
    const long long U = 16777216LL;
    short* ws  = (short*)d_ws;
    short* xt  = ws;            // [0,2U)  (dead after K1)
    short* rsz = ws + 2 * U;    // dead after K2b
    short* q1  = ws + 3 * U;
    short* k1  = ws + 4 * U;
    short* v1  = ws + 5 * U;
    short* o1  = ws + 6 * U;    // dead after K4b
    short* q2  = ws;            // reuse xt
    short* k2  = ws + U;
    short* v2  = ws + 2 * U;    // reuse rsz
    short* o2  = ws + 3 * U;    // reuse q1
    short* wb  = ws + 7 * U;    // bf16 pre-swizzled weight images (163840 elems)
    short* wWr  = wb;
    short* wWqw = wb + 32768;
    short* wWkw = wb + 49152;
    short* wWvw = wb + 65536;
    short* wWqh = wb + 81920;
    short* wWkh = wb + 98304;
    short* wWvh = wb + 114688;
    short* wWo  = wb + 131072;

    dim3 blk(256);

    wprep<<<dim3(16, 8), blk, 0, stream>>>(Wr, Wqw, Wkw, Wvw, Wqh, Wkh, Wvh, Wo, wb);
    xpose<<<dim3(256, 4, 8), blk, 0, stream>>>(x, xt);

    // K1: resized_t[b][r][w][h], per (b,w); K=256
    gemmw<1, 2, false><<<dim3(128, 1, 8), blk, 0, stream>>>(
        wWr, nullptr, br, nullptr,
        xt, 4194304LL, 256LL, 32768LL,
        rsz, nullptr, nullptr, 2097152LL, 128LL, 16384LL);

    // K2a: q1,k1[b][o][r][w], per (b,r)
    gemmw<2, 1, false><<<dim3(128, 1, 8), blk, 0, stream>>>(
        wWqw, wWkw, bqw, bkw,
        rsz, 2097152LL, 16384LL, 128LL,
        q1, k1, nullptr, 2097152LL, 128LL, 16384LL);

    // K2b: v1t[b][o][w][u], per (b,w)
    gemmw<1, 1, false><<<dim3(128, 1, 8), blk, 0, stream>>>(
        wWvw, nullptr, bvw, nullptr,
        rsz, 2097152LL, 128LL, 16384LL,
        v1, nullptr, nullptr, 2097152LL, 128LL, 16384LL);

    // K3: width attention -> out1[b][o][r][w]
    attnk<false><<<dim3(128, 1, 8), blk, 0, stream>>>(q1, k1, v1, o1);

    // K4a: q2t,k2t, per-block x
    gemmw<2, 1, false><<<dim3(128, 1, 8), blk, 0, stream>>>(
        wWqh, wWkh, bqh, bkh,
        o1, 2097152LL, 128LL, 16384LL,
        q2, k2, nullptr, 2097152LL, 128LL, 16384LL);

    // K4b: v2t
    gemmw<1, 1, false><<<dim3(128, 1, 8), blk, 0, stream>>>(
        wWvh, nullptr, bvh, nullptr,
        o1, 2097152LL, 16384LL, 128LL,
        v2, nullptr, nullptr, 2097152LL, 128LL, 16384LL);

    // K5: height attention -> out2st (transposed epilogue)
    attnk<true><<<dim3(128, 1, 8), blk, 0, stream>>>(q2, k2, v2, o2);

    // K6: restore -> out fp32, per (b,h'), 2 m-tiles
    gemmw<1, 1, true><<<dim3(128, 2, 8), blk, 0, stream>>>(
        wWo, nullptr, bo, nullptr,
        o2, 2097152LL, 128LL, 16384LL,
        nullptr, nullptr, out, 4194304LL, 128LL, 16384LL);
}

// Round 4
// 279.071 us; speedup vs baseline: 3.0550x; 1.0480x over previous
//
#include <hip/hip_runtime.h>
#include <hip/hip_bf16.h>

// CSAA on MFMA, round 4: no x-transpose pass. New n-fast B staging path
// (coalesced global loads -> in-register 8x8 transpose -> conflict-free
// ds_write_b128) lets every pass read its natural layout:
//  P1 : rsz[b][p][h][w]  per (b,hw128): M=p,N=hw,K=c(256)  B=x (fp32 n-fast)
//  P2a: q1,k1[b][o][p][w] per (b,p):    M=o,N=w,K=h        B=rsz (bf16 n-fast)
//  P2b: v1[b][o][u][w]   per (b,u):     M=o,N=w,K=h        B=rsz (bf16 n-fast)
//  P3 : T1[b][p][o][w]   per (b,o):     flash attn; V staged n-fast
//  P4a: q2,k2[b][o2][c][h] per (b,c):   M=o2,N=h,K=w       B=T1 (k-fast gload16)
//  P4b: v2[b][o2][u][h]  per (b,u):     M=o2,N=h,K=w       B=T1 (k-fast)
//  P5 : T2[b][h][o2][c]  per (b,o2):    flash attn, transposed epilogue
//  P6 : out[b][co][h][o2] per (b,h)x2:  M=co(256),N=o2,K=c B=T2 (k-fast), fp32

typedef __attribute__((ext_vector_type(8))) short bf16x8;
typedef __attribute__((ext_vector_type(4))) float f32x4;

__device__ __forceinline__ short f2b(float f) {
    __hip_bfloat16 h = __float2bfloat16(f);
    short s; __builtin_memcpy(&s, &h, 2);
    return s;
}

// Row-dependent XOR swizzle over 16B blocks. swx mixes row bit 3 so writers
// hitting rows 8-apart (n-fast transpose staging) still spread banks; readers
// (16 consecutive rows) stay <=2-way which is free.
__device__ __forceinline__ int swx(int row) { return (row ^ (row >> 3)) & 7; }
__device__ __forceinline__ int swzb(int row, int blk) {
    return (row << 7) + ((blk ^ swx(row)) << 3);
}

// async global->LDS, 16B per lane: LDS dest wave-uniform base + lane*16.
__device__ __forceinline__ void gload16(const void* g, void* l) {
    __builtin_amdgcn_global_load_lds(
        (const __attribute__((address_space(1))) void*)g,
        (__attribute__((address_space(3))) void*)l, 16, 0, 0);
}

// 64x64 wave tile over 128x128x128.
__device__ __forceinline__ void mfma64(const short* __restrict__ SA,
                                       const short* __restrict__ SB,
                                       f32x4 (&acc)[4][4], int lane,
                                       int wr64, int wc64) {
    #pragma unroll
    for (int kk = 0; kk < 4; kk++) {
        const int kb = kk * 4 + (lane >> 4);
        bf16x8 a[4], b[4];
        #pragma unroll
        for (int mi = 0; mi < 4; mi++)
            a[mi] = *(const bf16x8*)&SA[swzb(wr64 + mi * 16 + (lane & 15), kb)];
        #pragma unroll
        for (int ni = 0; ni < 4; ni++)
            b[ni] = *(const bf16x8*)&SB[swzb(wc64 + ni * 16 + (lane & 15), kb)];
        #pragma unroll
        for (int mi = 0; mi < 4; mi++)
            #pragma unroll
            for (int ni = 0; ni < 4; ni++)
                acc[mi][ni] = __builtin_amdgcn_mfma_f32_16x16x32_bf16(
                    a[mi], b[ni], acc[mi][ni], 0, 0, 0);
    }
}

// n-fast staging: source rows are k (n contiguous). Thread (t) owns k-block
// kb=t>>4 (8 k's) x n-octet n8=t&15: 8 coalesced loads, 8x8 register
// transpose, 8 ds_write_b128 (exactly 8 lanes/bank-group: conflict-free).
__device__ __forceinline__ void stage_nf_bf16(const short* __restrict__ Bb,
                                              long long b_r, int k0,
                                              short* __restrict__ Bs, int t) {
    const int n8 = t & 15, kb = t >> 4;
    bf16x8 rk[8];
    #pragma unroll
    for (int i = 0; i < 8; i++)
        rk[i] = *(const bf16x8*)(Bb + (long long)(k0 + kb * 8 + i) * b_r + n8 * 8);
    #pragma unroll
    for (int j = 0; j < 8; j++) {
        bf16x8 col;
        #pragma unroll
        for (int i = 0; i < 8; i++) col[i] = rk[i][j];
        *(bf16x8*)&Bs[swzb(n8 * 8 + j, kb)] = col;
    }
}

__device__ __forceinline__ void stage_nf_f32(const float* __restrict__ Bb,
                                             long long b_r, int k0,
                                             short* __restrict__ Bs, int t) {
    const int n8 = t & 15, kb = t >> 4;
    bf16x8 rk[8];
    #pragma unroll
    for (int i = 0; i < 8; i++) {
        const float* s = Bb + (long long)(k0 + kb * 8 + i) * b_r + n8 * 8;
        float4 v0 = *(const float4*)s, v1 = *(const float4*)(s + 4);
        rk[i][0] = f2b(v0.x); rk[i][1] = f2b(v0.y);
        rk[i][2] = f2b(v0.z); rk[i][3] = f2b(v0.w);
        rk[i][4] = f2b(v1.x); rk[i][5] = f2b(v1.y);
        rk[i][6] = f2b(v1.z); rk[i][7] = f2b(v1.w);
    }
    #pragma unroll
    for (int j = 0; j < 8; j++) {
        bf16x8 col;
        #pragma unroll
        for (int i = 0; i < 8; i++) col[i] = rk[i][j];
        *(bf16x8*)&Bs[swzb(n8 * 8 + j, kb)] = col;
    }
}

// ---------------- wprep: fp32 weights -> bf16 pre-swizzled images ----------
__global__ __launch_bounds__(256)
void wprep(const float* __restrict__ Wr, const float* __restrict__ Wqw,
           const float* __restrict__ Wkw, const float* __restrict__ Wvw,
           const float* __restrict__ Wqh, const float* __restrict__ Wkh,
           const float* __restrict__ Wvh, const float* __restrict__ Wo,
           short* __restrict__ dst) {
    const int id = blockIdx.y;
    const float* W; int M, K, off;
    switch (id) {
        case 0: W = Wr;  M = 128; K = 256; off = 0;      break;
        case 1: W = Wqw; M = 128; K = 128; off = 32768;  break;
        case 2: W = Wkw; M = 128; K = 128; off = 49152;  break;
        case 3: W = Wvw; M = 128; K = 128; off = 65536;  break;
        case 4: W = Wqh; M = 128; K = 128; off = 81920;  break;
        case 5: W = Wkh; M = 128; K = 128; off = 98304;  break;
        case 6: W = Wvh; M = 128; K = 128; off = 114688; break;
        default: W = Wo; M = 256; K = 128; off = 131072; break;
    }
    int g = blockIdx.x * 256 + threadIdx.x;
    if (g >= (M * K) >> 3) return;
    int gpr = K >> 3;
    int row = g / gpr;
    int blk = g - row * gpr;
    int ks = blk >> 4, bi = blk & 15;
    int my = row >> 7, r = row & 127;
    int nks = K >> 7;
    const float* s = W + (long long)row * K + blk * 8;
    float4 v0 = *(const float4*)s, v1 = *(const float4*)(s + 4);
    bf16x8 ov;
    ov[0] = f2b(v0.x); ov[1] = f2b(v0.y); ov[2] = f2b(v0.z); ov[3] = f2b(v0.w);
    ov[4] = f2b(v1.x); ov[5] = f2b(v1.y); ov[6] = f2b(v1.z); ov[7] = f2b(v1.w);
    *(bf16x8*)(dst + off + (my * nks + ks) * 16384 + swzb(r, bi)) = ov;
}

// ---------------- weight-GEMM ----------------
// BMODE: 0 = B k-fast (gload16 direct), 1 = B n-fast bf16, 2 = B n-fast fp32.
template<int NW, int KSTEPS, int BMODE, bool F32OUT>
__global__ __launch_bounds__(256)
void gemmw(const short* __restrict__ A0, const short* __restrict__ A1,
           const float* __restrict__ bias0, const float* __restrict__ bias1,
           const void* __restrict__ Bsrc, long long b_z, long long b_x, long long b_r,
           short* __restrict__ C0, short* __restrict__ C1, float* __restrict__ Cf,
           long long c_z, long long c_x, long long c_m) {
    __shared__ short As[16384];
    __shared__ short Bs[16384];
    const int t = threadIdx.x;
    const int lane = t & 63;
    const int wid = t >> 6;
    const int wr64 = (wid >> 1) * 64, wc64 = (wid & 1) * 64;
    const int bx = blockIdx.x, my = blockIdx.y, bz = blockIdx.z;

    f32x4 acc[NW][4][4];
    #pragma unroll
    for (int g = 0; g < NW; g++)
        #pragma unroll
        for (int mi = 0; mi < 4; mi++)
            #pragma unroll
            for (int ni = 0; ni < 4; ni++)
                acc[g][mi][ni] = (f32x4){0.f, 0.f, 0.f, 0.f};

    for (int ks = 0; ks < KSTEPS; ks++) {
        if (BMODE == 0) {
            const short* Bb = (const short*)Bsrc + bz * b_z + bx * b_x;
            #pragma unroll
            for (int i = 0; i < 8; i++) {
                int q = wid * 8 + i;
                int row = q * 4 + (lane >> 4);
                gload16(Bb + (long long)row * b_r + ks * 128
                           + (((lane & 15) ^ swx(row)) << 3), &Bs[q * 512]);
            }
        } else if (BMODE == 1) {
            stage_nf_bf16((const short*)Bsrc + bz * b_z + bx * b_x, b_r,
                          ks * 128, Bs, t);
        } else {
            stage_nf_f32((const float*)Bsrc + bz * b_z + bx * b_x, b_r,
                         ks * 128, Bs, t);
        }
        #pragma unroll
        for (int g = 0; g < NW; g++) {
            const short* Ai = ((g == 0) ? A0 : A1) + (my * KSTEPS + ks) * 16384;
            #pragma unroll
            for (int i = 0; i < 8; i++) {
                int q = wid * 8 + i;
                gload16(Ai + q * 512 + lane * 8, &As[q * 512]);
            }
            __syncthreads();
            mfma64(As, Bs, acc[g], lane, wr64, wc64);
            __syncthreads();
        }
    }

    if (F32OUT) {
        float* Cb = Cf + bz * c_z + bx * c_x;
        #pragma unroll
        for (int mi = 0; mi < 4; mi++)
            #pragma unroll
            for (int r = 0; r < 4; r++) {
                int rl = wr64 + mi * 16 + (lane >> 4) * 4 + r;
                int row = my * 128 + rl;
                float bb = bias0[row];
                #pragma unroll
                for (int ni = 0; ni < 4; ni++) {
                    int col = wc64 + ni * 16 + (lane & 15);
                    Cb[(long long)row * c_m + col] = acc[0][mi][ni][r] + bb;
                }
            }
    } else {
        #pragma unroll
        for (int g = 0; g < NW; g++) {
            const float* bias = (g == 0) ? bias0 : bias1;
            #pragma unroll
            for (int mi = 0; mi < 4; mi++)
                #pragma unroll
                for (int r = 0; r < 4; r++) {
                    int row = wr64 + mi * 16 + (lane >> 4) * 4 + r;
                    float bb = bias[row];
                    #pragma unroll
                    for (int ni = 0; ni < 4; ni++) {
                        int col = wc64 + ni * 16 + (lane & 15);
                        As[swzb(row, col >> 3) + (col & 7)] = f2b(acc[g][mi][ni][r] + bb);
                    }
                }
            __syncthreads();
            short* Cg = ((g == 0) ? C0 : C1) + bz * c_z + bx * c_x;
            #pragma unroll
            for (int i = 0; i < 8; i++) {
                int idx = t + i * 256;
                int row = idx >> 4, ch = idx & 15;
                *(bf16x8*)(Cg + (long long)row * c_m + ch * 8) =
                    *(const bf16x8*)&As[swzb(row, ch)];
            }
            __syncthreads();
        }
    }
}

// ---------------- fused attention per (b,o) ----------------
// Q,K panels k-fast (gload16). V panel is [u][h/w] (k=u along rows) -> staged
// n-fast with the register-transpose path. Output row stride 16384, col base
// bx*128 (T1[b][p][o][w] / T2[b][h][o2][c] layouts).
template<bool TEPI>
__global__ __launch_bounds__(256)
void attnk(const short* __restrict__ Q, const short* __restrict__ Kp,
           const short* __restrict__ V, short* __restrict__ O) {
    __shared__ short SA[16384];
    __shared__ short SB[16384];
    __shared__ float pmax[2][128];
    __shared__ float psum[2][128];
    const int t = threadIdx.x;
    const int lane = t & 63;
    const int wid = t >> 6;
    const int wr64 = (wid >> 1) * 64, wc64 = (wid & 1) * 64, wch = wid & 1;
    const long long poff = (long long)blockIdx.z * 2097152LL
                         + (long long)blockIdx.x * 16384LL;
    const short* Qb = Q + poff;
    const short* Kb = Kp + poff;
    const short* Vb = V + poff;
    short* Ob = O + (long long)blockIdx.z * 2097152LL + (long long)blockIdx.x * 128LL;

    #pragma unroll
    for (int i = 0; i < 8; i++) {
        int q = wid * 8 + i;
        int row = q * 4 + (lane >> 4);
        int sw = (((lane & 15) ^ swx(row)) << 3);
        gload16(Qb + row * 128 + sw, &SA[q * 512]);
        gload16(Kb + row * 128 + sw, &SB[q * 512]);
    }
    __syncthreads();

    f32x4 acc[4][4];
    #pragma unroll
    for (int mi = 0; mi < 4; mi++)
        #pragma unroll
        for (int ni = 0; ni < 4; ni++) acc[mi][ni] = (f32x4){0.f, 0.f, 0.f, 0.f};
    mfma64(SA, SB, acc, lane, wr64, wc64);

    // wave-partial row max over this wave's 64 cols
    #pragma unroll
    for (int mi = 0; mi < 4; mi++)
        #pragma unroll
        for (int r = 0; r < 4; r++) {
            float mx = fmaxf(fmaxf(acc[mi][0][r], acc[mi][1][r]),
                             fmaxf(acc[mi][2][r], acc[mi][3][r]));
            #pragma unroll
            for (int d = 1; d < 16; d <<= 1) mx = fmaxf(mx, __shfl_xor(mx, d, 64));
            if ((lane & 15) == 0)
                pmax[wch][wr64 + mi * 16 + (lane >> 4) * 4 + r] = mx;
        }
    __syncthreads();   // bar1: maxes visible; SA/SB panel reads complete

    // issue V loads early (regs; latency hides under softmax VALU)
    const int n8 = t & 15, kb = t >> 4;
    bf16x8 vk[8];
    #pragma unroll
    for (int i = 0; i < 8; i++)
        vk[i] = *(const bf16x8*)(Vb + (kb * 8 + i) * 128 + n8 * 8);

    // exp (unscaled), partial sums, scatter P -> SA
    #pragma unroll
    for (int mi = 0; mi < 4; mi++)
        #pragma unroll
        for (int r = 0; r < 4; r++) {
            int row = wr64 + mi * 16 + (lane >> 4) * 4 + r;
            float M = fmaxf(pmax[0][row], pmax[1][row]);
            float p[4], s = 0.f;
            #pragma unroll
            for (int ni = 0; ni < 4; ni++) {
                p[ni] = __expf(acc[mi][ni][r] - M);
                s += p[ni];
            }
            #pragma unroll
            for (int d = 1; d < 16; d <<= 1) s += __shfl_xor(s, d, 64);
            if ((lane & 15) == 0) psum[wch][row] = s;
            #pragma unroll
            for (int ni = 0; ni < 4; ni++) {
                int col = wc64 + ni * 16 + (lane & 15);
                SA[swzb(row, col >> 3) + (col & 7)] = f2b(p[ni]);
            }
        }
    // transpose V into SB (B[n][k=u], conflict-free b128 writes)
    #pragma unroll
    for (int j = 0; j < 8; j++) {
        bf16x8 col;
        #pragma unroll
        for (int i = 0; i < 8; i++) col[i] = vk[i][j];
        *(bf16x8*)&SB[swzb(n8 * 8 + j, kb)] = col;
    }
    __syncthreads();   // bar2: P in SA, V in SB, psum visible

    f32x4 acc2[4][4];
    #pragma unroll
    for (int mi = 0; mi < 4; mi++)
        #pragma unroll
        for (int ni = 0; ni < 4; ni++) acc2[mi][ni] = (f32x4){0.f, 0.f, 0.f, 0.f};
    mfma64(SA, SB, acc2, lane, wr64, wc64);
    __syncthreads();   // bar3: SB free for output bounce

    #pragma unroll
    for (int mi = 0; mi < 4; mi++)
        #pragma unroll
        for (int r = 0; r < 4; r++) {
            int row = wr64 + mi * 16 + (lane >> 4) * 4 + r;
            float rinv = 1.f / (psum[0][row] + psum[1][row]);
            #pragma unroll
            for (int ni = 0; ni < 4; ni++) {
                int col = wc64 + ni * 16 + (lane & 15);
                short vv = f2b(acc2[mi][ni][r] * rinv);
                if (!TEPI) SB[swzb(row, col >> 3) + (col & 7)] = vv;
                else       SB[swzb(col, row >> 3) + (row & 7)] = vv;
            }
        }
    __syncthreads();
    #pragma unroll
    for (int i = 0; i < 8; i++) {
        int idx = t + i * 256;
        int row = idx >> 4, ch = idx & 15;
        *(bf16x8*)(Ob + (long long)row * 16384 + ch * 8) =
            *(const bf16x8*)&SB[swzb(row, ch)];
    }
}

extern "C" void kernel_launch(void* const* d_in, const int* in_sizes, int n_in,
                              void* d_out, int out_size, void* d_ws, size_t ws_size,
                              hipStream_t stream) {
    const float* x   = (const float*)d_in[0];
    const float* Wr  = (const float*)d_in[1];
    const float* br  = (const float*)d_in[2];
    const float* Wqw = (const float*)d_in[3];
    const float* bqw = (const float*)d_in[4];
    const float* Wkw = (const float*)d_in[5];
    const float* bkw = (const float*)d_in[6];
    const float* Wvw = (const float*)d_in[7];
    const float* bvw = (const float*)d_in[8];
    const float* Wqh = (const float*)d_in[9];
    const float* bqh = (const float*)d_in[10];
    const float* Wkh = (const float*)d_in[11];
    const float* bkh = (const float*)d_in[12];
    const float* Wvh = (const float*)d_in[13];
    const float* bvh = (const float*)d_in[14];
    const float* Wo  = (const float*)d_in[15];
    const float* bo  = (const float*)d_in[16];
    float* out = (float*)d_out;
    (void)in_sizes; (void)n_in; (void)out_size; (void)ws_size;

    // bf16 workspace, U = 8*128^3 elems (33.5MB). Liveness-packed: 4U + weights.
    // s0: rsz -> T1 -> T2 ; s1: q1 -> q2 ; s2: k1 -> k2 ; s3: v1 -> v2.
    const long long U = 16777216LL;
    short* ws = (short*)d_ws;
    short* s0 = ws;
    short* s1 = ws + U;
    short* s2 = ws + 2 * U;
    short* s3 = ws + 3 * U;
    short* wb = ws + 4 * U;
    short* wWr  = wb;
    short* wWqw = wb + 32768;
    short* wWkw = wb + 49152;
    short* wWvw = wb + 65536;
    short* wWqh = wb + 81920;
    short* wWkh = wb + 98304;
    short* wWvh = wb + 114688;
    short* wWo  = wb + 131072;

    dim3 blk(256);

    wprep<<<dim3(16, 8), blk, 0, stream>>>(Wr, Wqw, Wkw, Wvw, Wqh, Wkh, Wvh, Wo, wb);

    // P1: rsz[b][p][h][w] <- x, per (b,hw-tile); B fp32 n-fast, K=256
    gemmw<1, 2, 2, false><<<dim3(128, 1, 8), blk, 0, stream>>>(
        wWr, nullptr, br, nullptr,
        x, 4194304LL, 128LL, 16384LL,
        s0, nullptr, nullptr, 2097152LL, 128LL, 16384LL);

    // P2a: q1,k1[b][o][p][w], per (b,p); B = rsz bf16 n-fast (contract h)
    gemmw<2, 1, 1, false><<<dim3(128, 1, 8), blk, 0, stream>>>(
        wWqw, wWkw, bqw, bkw,
        s0, 2097152LL, 16384LL, 128LL,
        s1, s2, nullptr, 2097152LL, 128LL, 16384LL);

    // P2b: v1[b][o][u][w], per (b,u)
    gemmw<1, 1, 1, false><<<dim3(128, 1, 8), blk, 0, stream>>>(
        wWvw, nullptr, bvw, nullptr,
        s0, 2097152LL, 16384LL, 128LL,
        s3, nullptr, nullptr, 2097152LL, 128LL, 16384LL);

    // P3: width attention -> T1[b][p][o][w] (into s0; rsz dead)
    attnk<false><<<dim3(128, 1, 8), blk, 0, stream>>>(s1, s2, s3, s0);

    // P4a: q2,k2[b][o2][c][h], per (b,c); B = T1 k-fast
    gemmw<2, 1, 0, false><<<dim3(128, 1, 8), blk, 0, stream>>>(
        wWqh, wWkh, bqh, bkh,
        s0, 2097152LL, 16384LL, 128LL,
        s1, s2, nullptr, 2097152LL, 128LL, 16384LL);

    // P4b: v2[b][o2][u][h], per (b,u)
    gemmw<1, 1, 0, false><<<dim3(128, 1, 8), blk, 0, stream>>>(
        wWvh, nullptr, bvh, nullptr,
        s0, 2097152LL, 16384LL, 128LL,
        s3, nullptr, nullptr, 2097152LL, 128LL, 16384LL);

    // P5: height attention -> T2[b][h][o2][c] (into s0; T1 dead)
    attnk<true><<<dim3(128, 1, 8), blk, 0, stream>>>(s1, s2, s3, s0);

    // P6: out[b][co][h][o2] fp32, per (b,h), 2 m-tiles; B = T2 k-fast
    gemmw<1, 1, 0, true><<<dim3(128, 2, 8), blk, 0, stream>>>(
        wWo, nullptr, bo, nullptr,
        s0, 2097152LL, 16384LL, 128LL,
        nullptr, nullptr, out, 4194304LL, 128LL, 16384LL);
}